// Round 9
// baseline (273.750 us; speedup 1.0000x reference)
//
#include <hip/hip_runtime.h>
#include <hip/hip_bf16.h>

#define N_NODES 8192
#define D_FEAT 128

// ws layout: [0, 2MiB) = zn (normalized bf16, pre-swizzled tiles);
// [2MiB] int cnt; [2MiB+16) int4 list[LIST_CAP] for deferred cold pairs.
#define ZN_BYTES (2u * 1024u * 1024u)
#define LIST_CAP 1024
#define NCOMPUTE 442   // sum_{k=1..64} ceil(k/5): triangle column-chunks of <=5

typedef __bf16 bf16x8 __attribute__((ext_vector_type(8)));
typedef float f32x4 __attribute__((ext_vector_type(4)));

// ---- barriers ----
__device__ __forceinline__ void vm0_barrier() {
  asm volatile("s_waitcnt vmcnt(0) lgkmcnt(0)\n\ts_barrier" ::: "memory");
}

// Async global->LDS, 16B/lane, linear dest (wave-uniform base + lane*16 —
// satisfied by chunk = i*256 + tid addressing; refcheck-validated R12-R19).
__device__ __forceinline__ void async_copy16(void* lds, const void* g) {
  __builtin_amdgcn_global_load_lds(
      (const __attribute__((address_space(1))) void*)g,
      (__attribute__((address_space(3))) void*)lds, 16, 0, 0);
}

// ---- cold path (fixup kernel only — never called from sim, so sim's
// register allocation is unconstrained; R12/R16 lesson). Never taken for
// the given Gaussian inputs: max off-diag cosine ~0.49 << 0.75.
__device__ __attribute__((noinline)) bool lsh_collide(
    const float* __restrict__ z, const float* __restrict__ H, int i, int j) {
  for (int b = 0; b < 64; ++b) {          // 64 bands x 8 bits
    unsigned ci = 0, cj = 0;
    for (int bit = 0; bit < 8; ++bit) {
      int col = b * 8 + bit;
      float di = 0.f, dj = 0.f;
      for (int k = 0; k < D_FEAT; ++k) {
        float h = H[(size_t)k * 512 + col];
        di += z[(size_t)i * D_FEAT + k] * h;
        dj += z[(size_t)j * D_FEAT + k] * h;
      }
      if (di > 0.f) ci |= (1u << bit);
      if (dj > 0.f) cj |= (1u << bit);
    }
    if (ci == cj) return true;
  }
  return false;
}

__device__ __forceinline__ unsigned pack_bf16x2(float x, float y) {
  __hip_bfloat16 bx = __float2bfloat16(x), by = __float2bfloat16(y);
  return (unsigned)(*(unsigned short*)&bx) |
         ((unsigned)(*(unsigned short*)&by) << 16);
}

// ---- pre-kernel: normalize z -> bf16 in the PRE-SWIZZLED tile layout
// (16B chunk c of row r of tile blk at zn[blk*2048 + r*16 + (c^(r&15))]).
// Layout + rounding refcheck-validated (R13-R19). Also zeroes the cold
// counter (ws is poisoned each iteration).
__global__ __launch_bounds__(256) void norm_kernel(const float* __restrict__ z,
                                                   uint4* __restrict__ zn,
                                                   int* __restrict__ cnt) {
  if (blockIdx.x == 0 && threadIdx.x == 0) *cnt = 0;
  int gt = (int)blockIdx.x * 256 + (int)threadIdx.x;
  int row = gt >> 3, oct = gt & 7;        // 8 lanes per row
  const float4* src = (const float4*)(z + (size_t)row * D_FEAT + oct * 16);
  float4 v[4];
#pragma unroll
  for (int c = 0; c < 4; ++c) v[c] = src[c];
  float ss = 0.f;
#pragma unroll
  for (int c = 0; c < 4; ++c)
    ss += v[c].x * v[c].x + v[c].y * v[c].y + v[c].z * v[c].z + v[c].w * v[c].w;
  ss += __shfl_xor(ss, 1);
  ss += __shfl_xor(ss, 2);
  ss += __shfl_xor(ss, 4);
  float inv = rsqrtf(ss);
  int blk = row >> 7, r = row & 127;
  uint4* dst = zn + (size_t)blk * 2048 + r * 16;
#pragma unroll
  for (int c2 = 0; c2 < 2; ++c2) {
    float4 a = v[2 * c2], b = v[2 * c2 + 1];
    uint4 o;
    o.x = pack_bf16x2(a.x * inv, a.y * inv);
    o.y = pack_bf16x2(a.z * inv, a.w * inv);
    o.z = pack_bf16x2(b.x * inv, b.y * inv);
    o.w = pack_bf16x2(b.z * inv, b.w * inv);
    dst[(oct * 2 + c2) ^ (r & 15)] = o;
  }
}

// ---- main kernel (R20): STORE-FREE triangle compute.
// The 256MiB zero background is written by hipMemsetAsync (the rocclr fill
// kernel, ~6.5 TB/s — measured 1GiB/165us), which completes before sim
// (stream order) -> sim safely writes ONLY the 8192 diagonal ones (the one
// block per bn owning the bm==bn tile) plus cold-candidate list appends.
// All R14-R19 evidence: sim-internal bulk stores run at only ~3 TB/s
// regardless of pattern/compute volume — so don't do bulk stores here.
// Triangle mapping (R19, verified): block b<442 owns bn-column chunk of
// <=5 A-tiles; B(bn) fragments register-resident (fbr[16], no spill).
__global__ __launch_bounds__(256, 2) void sim_kernel(const uint4* __restrict__ zn,
                                                     float* __restrict__ out,
                                                     int* __restrict__ cnt,
                                                     int4* __restrict__ list) {
  __shared__ __align__(16) unsigned char smem[65536];   // buf0 | buf1 (32KB each)

  int tid = threadIdx.x;
  int b = (int)blockIdx.x;

  // ---- triangle mapping: block b -> (bn, bm0..bm0+4 clipped to <=bn).
  // prefix(bn=5a+r) = 5a(a+1)/2 + r(a+1); solve a, then r, c.
  int a = (int)((sqrtf(40.0f * (float)b + 25.0f) - 5.0f) * 0.1f);
  while (5 * (a + 1) * (a + 2) / 2 <= b) ++a;
  while (a > 0 && 5 * a * (a + 1) / 2 > b) --a;
  int rem = b - 5 * a * (a + 1) / 2;
  int ap1 = a + 1;
  int r = rem / ap1;
  int c = rem - r * ap1;
  int bn = 5 * a + r;                 // 0..63
  int bm0 = 5 * c;                    // chunk start; tiles bm0..bm0+4 (clipped)

  int wv = tid >> 6, lane = tid & 63;
  int wm = (wv >> 1) * 64, wn = (wv & 1) * 64;
  int m16 = lane & 15, g = lane >> 4;

  // ---- prologue: B(bn) -> buf1, A(bm0) -> buf0, both via gl_lds.
  {
    const uint4* gB = zn + (size_t)bn * 2048;
    const uint4* gA = zn + (size_t)bm0 * 2048;
#pragma unroll
    for (int i = 0; i < 8; ++i) {
      int cc = i * 256 + tid;
      async_copy16(smem + 32768 + cc * 16, gB + cc);
      async_copy16(smem + cc * 16, gA + cc);
    }
  }
  vm0_barrier();

  // Hoist B fragments into registers (chunk-invariant; statically indexed).
  // buf1 becomes the odd-parity As buffer after this (safe: every wave's
  // fbr ds_reads complete before buf1 overwrite via t=0's barrier).
  bf16x8 fbr[16];
  {
    unsigned short (*Bs)[128] = (unsigned short (*)[128])(smem + 32768);
#pragma unroll
    for (int kc = 0; kc < 4; ++kc) {
      int cs = ((kc * 4 + g) ^ m16) * 8;
#pragma unroll
      for (int tt = 0; tt < 4; ++tt)
        fbr[kc * 4 + tt] = *(const bf16x8*)&Bs[wn + tt * 16 + m16][cs];
    }
  }

  for (int t = 0; t < 5; ++t) {
    int bm = bm0 + t;
    bool live = (bm <= bn);                          // block-uniform
    unsigned char* cur = smem + (t & 1) * 32768;
    unsigned char* nxt = smem + ((t + 1) & 1) * 32768;

    // Iter-top: my gl_lds(t) retired and ALL waves' ds_reads of buf(t-1)
    // done -> safe to overwrite buf(t-1) and read As(t). (No bulk stores
    // exist anymore, so a full vmcnt(0) drain is harmless.)
    vm0_barrier();

    // Async-stage A(bm+1) — concurrent with everything below.
    if (t < 4 && bm + 1 <= bn) {
      const uint4* gA = zn + (size_t)(bm + 1) * 2048;
#pragma unroll
      for (int i = 0; i < 8; ++i) {
        int cc = i * 256 + tid;
        async_copy16(nxt + cc * 16, gA + cc);
      }
    }

    if (live) {
      // ---- diagonal ones: exactly one block owns the bm==bn tile; its
      // 128 scalar stores land on the memset background (stream-ordered).
      if (bm == bn && tid < 128) {
        int d = bn * 128 + tid;
        out[(size_t)d * N_NODES + d] = 1.0f;
      }

      // ---- MFMA: wave -> 64x64 quadrant, 4x4 tiles of 16x16x32, K=128 ----
      unsigned short (*As)[128] = (unsigned short (*)[128])cur;
      f32x4 acc[4][4] = {};
#pragma unroll
      for (int kc = 0; kc < 4; ++kc) {
        bf16x8 fa[4];
        int cs = ((kc * 4 + g) ^ m16) * 8;
#pragma unroll
        for (int tt = 0; tt < 4; ++tt)
          fa[tt] = *(const bf16x8*)&As[wm + tt * 16 + m16][cs];
#pragma unroll
        for (int tm = 0; tm < 4; ++tm)
#pragma unroll
          for (int tn = 0; tn < 4; ++tn)
            acc[tm][tn] = __builtin_amdgcn_mfma_f32_16x16x32_bf16(fa[tm], fbr[kc * 4 + tn], acc[tm][tn], 0, 0, 0);
      }

      // ---- candidate scan (no S stores). col=lane&15, row=g*4+r.
      // Mirror-emit for bm<bn so the triangle covers both orders.
#pragma unroll
      for (int tm = 0; tm < 4; ++tm)
#pragma unroll
        for (int tn = 0; tn < 4; ++tn) {
          f32x4 cc = acc[tm][tn];
          float m4 = fmaxf(fmaxf(cc[0], cc[1]), fmaxf(cc[2], cc[3]));
          if (m4 > 0.75f) {
            int j = bn * 128 + wn + tn * 16 + m16;
#pragma unroll
            for (int rr = 0; rr < 4; ++rr) {
              int i = bm * 128 + wm + tm * 16 + g * 4 + rr;
              if (i != j && cc[rr] > 0.75f) {
                int idx = atomicAdd(cnt, 1);
                if (idx < LIST_CAP)
                  list[idx] = make_int4(i, j, __float_as_int(cc[rr]), 0);
                if (bm < bn) {
                  int idx2 = atomicAdd(cnt, 1);
                  if (idx2 < LIST_CAP)
                    list[idx2] = make_int4(j, i, __float_as_int(cc[rr]), 0);
                }
              }
            }
          }
        }
    }
  }
}

// ---- cold fixup: resolve deferred (i,j,s) candidates (empty in practice);
// separate launch: its patch writes are ordered after sim's diagonal writes
// and the memset by kernel boundaries.
__global__ __launch_bounds__(256) void fixup_kernel(const float* __restrict__ z,
                                                    const float* __restrict__ H,
                                                    const int* __restrict__ cnt,
                                                    const int4* __restrict__ list,
                                                    float* __restrict__ out) {
  int n = *cnt;
  if (n > LIST_CAP) n = LIST_CAP;
  for (int e = (int)threadIdx.x; e < n; e += 256) {
    int i = list[e].x, j = list[e].y;
    float s = __int_as_float(list[e].z);
    if (lsh_collide(z, H, i, j)) out[(size_t)i * N_NODES + j] = s;
  }
}

extern "C" void kernel_launch(void* const* d_in, const int* in_sizes, int n_in,
                              void* d_out, int out_size, void* d_ws, size_t ws_size,
                              hipStream_t stream) {
  const float* z = (const float*)d_in[0];   // [8192, 128] fp32
  const float* H = (const float*)d_in[1];   // [128, 512] fp32
  // d_in[2] = edge_index, unused by the reference forward.
  float* out = (float*)d_out;               // [8192, 8192] fp32
  unsigned char* ws = (unsigned char*)d_ws;
  uint4* zn = (uint4*)ws;                   // 2 MiB normalized bf16, pre-swizzled
  int* cnt = (int*)(ws + ZN_BYTES);
  int4* list = (int4*)(ws + ZN_BYTES + 16);
  (void)ws_size;

  // Zero background via the rocclr fill kernel (~6.5 TB/s; stream-ordered,
  // graph-capturable). sim/fixup write only diagonal + cold patches on top.
  hipMemsetAsync(out, 0, (size_t)N_NODES * N_NODES * sizeof(float), stream);
  norm_kernel<<<256, 256, 0, stream>>>(z, zn, cnt);
  sim_kernel<<<NCOMPUTE, 256, 0, stream>>>(zn, out, cnt, list);
  fixup_kernel<<<1, 256, 0, stream>>>(z, H, cnt, list, out);
}

// Round 12
// 267.179 us; speedup vs baseline: 1.0246x; 1.0246x over previous
//
#include <hip/hip_runtime.h>
#include <hip/hip_bf16.h>

#define N_NODES 8192
#define D_FEAT 128

// ws layout: [0, 2MiB) = zn (normalized bf16, pre-swizzled tiles).
#define COLD_CAP 63

typedef __bf16 bf16x8 __attribute__((ext_vector_type(8)));
typedef float f32x4 __attribute__((ext_vector_type(4)));

// ---- barriers (raw s_barrier; never drain vmcnt to 0 inside the loop) ----
__device__ __forceinline__ void lgkm_barrier() {
  asm volatile("s_waitcnt lgkmcnt(0)\n\ts_barrier" ::: "memory");
}
// Tile-top: per-wave FIFO is [8 gl_lds(t)][16 stores(t-1)] -> vmcnt(16)
// retires exactly the staging loads (+ older stores), never the youngest 16
// stores. lgkmcnt(0)+barrier also proves all waves' ds_reads of the previous
// As buffer are done -> safe to gl_lds-overwrite it.
__device__ __forceinline__ void stage_barrier() {
  asm volatile("s_waitcnt vmcnt(16) lgkmcnt(0)\n\ts_barrier" ::: "memory");
}
__device__ __forceinline__ void vm0_barrier() {
  asm volatile("s_waitcnt vmcnt(0) lgkmcnt(0)\n\ts_barrier" ::: "memory");
}
__device__ __forceinline__ void lgkm_fence() {
  asm volatile("s_waitcnt lgkmcnt(0)" ::: "memory");
}

// Async global->LDS, 16B/lane, linear dest (wave-uniform base + lane*16 —
// satisfied by chunk = i*256 + tid addressing; refcheck-validated R12-R20).
__device__ __forceinline__ void async_copy16(void* lds, const void* g) {
  __builtin_amdgcn_global_load_lds(
      (const __attribute__((address_space(1))) void*)g,
      (__attribute__((address_space(3))) void*)lds, 16, 0, 0);
}

// ---- cold path: called ONLY from the post-loop tail, where fbr/acc are
// dead -> no live-across-call register poisoning of the hot loop (R12/R16
// lesson). Never taken for the given Gaussian inputs (max off-diag cosine
// ~0.49 << 0.75).
__device__ __attribute__((noinline)) bool lsh_collide(
    const float* __restrict__ z, const float* __restrict__ H, int i, int j) {
  for (int b = 0; b < 64; ++b) {          // 64 bands x 8 bits
    unsigned ci = 0, cj = 0;
    for (int bit = 0; bit < 8; ++bit) {
      int col = b * 8 + bit;
      float di = 0.f, dj = 0.f;
      for (int k = 0; k < D_FEAT; ++k) {
        float h = H[(size_t)k * 512 + col];
        di += z[(size_t)i * D_FEAT + k] * h;
        dj += z[(size_t)j * D_FEAT + k] * h;
      }
      if (di > 0.f) ci |= (1u << bit);
      if (dj > 0.f) cj |= (1u << bit);
    }
    if (ci == cj) return true;
  }
  return false;
}

__device__ __forceinline__ unsigned pack_bf16x2(float x, float y) {
  __hip_bfloat16 bx = __float2bfloat16(x), by = __float2bfloat16(y);
  return (unsigned)(*(unsigned short*)&bx) |
         ((unsigned)(*(unsigned short*)&by) << 16);
}

// ---- pre-kernel: normalize z -> bf16 in the PRE-SWIZZLED tile layout
// (16B chunk c of row r of tile blk at zn[blk*2048 + r*16 + (c^(r&15))]).
// Layout + rounding refcheck-validated (R13-R20).
__global__ __launch_bounds__(256) void norm_kernel(const float* __restrict__ z,
                                                   uint4* __restrict__ zn) {
  int gt = (int)blockIdx.x * 256 + (int)threadIdx.x;
  int row = gt >> 3, oct = gt & 7;        // 8 lanes per row
  const float4* src = (const float4*)(z + (size_t)row * D_FEAT + oct * 16);
  float4 v[4];
#pragma unroll
  for (int c = 0; c < 4; ++c) v[c] = src[c];
  float ss = 0.f;
#pragma unroll
  for (int c = 0; c < 4; ++c)
    ss += v[c].x * v[c].x + v[c].y * v[c].y + v[c].z * v[c].z + v[c].w * v[c].w;
  ss += __shfl_xor(ss, 1);
  ss += __shfl_xor(ss, 2);
  ss += __shfl_xor(ss, 4);
  float inv = rsqrtf(ss);
  int blk = row >> 7, r = row & 127;
  uint4* dst = zn + (size_t)blk * 2048 + r * 16;
#pragma unroll
  for (int c2 = 0; c2 < 2; ++c2) {
    float4 a = v[2 * c2], b = v[2 * c2 + 1];
    uint4 o;
    o.x = pack_bf16x2(a.x * inv, a.y * inv);
    o.y = pack_bf16x2(a.z * inv, a.w * inv);
    o.z = pack_bf16x2(b.x * inv, b.y * inv);
    o.w = pack_bf16x2(b.z * inv, b.w * inv);
    dst[(oct * 2 + c2) ^ (r & 15)] = o;
  }
}

// ---- main kernel (R22): R14 hot path VERBATIM (best verified, 267.6us)
// + self-contained cold path: candidates go to a small LDS list; after the
// main loop every wave drains its stores (vmcnt 0), __syncthreads, then the
// block resolves its own candidates with lsh_collide and patches s over the
// earlier 0 (same block -> same CU/L2, drain-ordered; the mirror (j,i) is
// found independently by the mirror tile's owner since S is symmetric).
// This deletes the fixup dispatch + one launch boundary. No global cnt/list.
__global__ __launch_bounds__(256, 2) void sim_kernel(const uint4* __restrict__ zn,
                                                     const float* __restrict__ z,
                                                     const float* __restrict__ H,
                                                     float* __restrict__ out) {
  __shared__ __align__(16) unsigned char smem[65536];   // buf0 | buf1 (32KB each)
  __shared__ int cold_cnt;
  __shared__ int4 cold_list[COLD_CAP];

  int tid = threadIdx.x;
  int b = (int)blockIdx.x;
  int bm0 = b & 7;                // XCD id under round-robin dispatch
  int bn = b >> 3;                // 0..63

  int wv = tid >> 6, lane = tid & 63;
  int wm = (wv >> 1) * 64, wn = (wv & 1) * 64;
  int m16 = lane & 15, g = lane >> 4;

  if (tid == 0) cold_cnt = 0;

  // ---- prologue: Bs(bn) -> buf1, As(tile0) -> buf0, both via gl_lds.
  {
    const uint4* gB = zn + (size_t)bn * 2048;
    const uint4* gA = zn + (size_t)(bm0 * 8) * 2048;
#pragma unroll
    for (int i = 0; i < 8; ++i) {
      int c = i * 256 + tid;
      async_copy16(smem + 32768 + c * 16, gB + c);
      async_copy16(smem + c * 16, gA + c);
    }
  }
  vm0_barrier();

  // Hoist B fragments into registers (tile-invariant; statically indexed).
  // buf1 becomes the odd-parity As buffer after this (safe: every wave's
  // fbr ds_reads complete before buf1 overwrite via t=0's lgkm+barrier).
  bf16x8 fbr[16];
  {
    unsigned short (*Bs)[128] = (unsigned short (*)[128])(smem + 32768);
#pragma unroll
    for (int kc = 0; kc < 4; ++kc) {
      int cs = ((kc * 4 + g) ^ m16) * 8;
#pragma unroll
      for (int tt = 0; tt < 4; ++tt)
        fbr[kc * 4 + tt] = *(const bf16x8*)&Bs[wn + tt * 16 + m16][cs];
    }
  }

  for (int t = 0; t < 8; ++t) {
    int bm = bm0 * 8 + t;
    unsigned char* cur = smem + (t & 1) * 32768;
    unsigned char* nxt = smem + ((t + 1) & 1) * 32768;

    // B1: my gl_lds(t) retired (vmcnt 16; youngest stores stay in flight)
    // and ALL waves' ds_reads of buf(t-1) done (lgkm 0 + barrier).
    stage_barrier();

    // Async-stage As(t+1) — concurrent with everything below.
    if (t < 7) {
      const uint4* gA = zn + (size_t)(bm + 1) * 2048;
#pragma unroll
      for (int i = 0; i < 8; ++i) {
        int c = i * 256 + tid;
        async_copy16(nxt + c * 16, gA + c);
      }
    }

    // ---- MFMA: wave -> 64x64 quadrant, 4x4 tiles of 16x16x32, K=128 ----
    unsigned short (*As)[128] = (unsigned short (*)[128])cur;
    f32x4 acc[4][4] = {};
#pragma unroll
    for (int kc = 0; kc < 4; ++kc) {
      bf16x8 fa[4];
      int cs = ((kc * 4 + g) ^ m16) * 8;
#pragma unroll
      for (int tt = 0; tt < 4; ++tt)
        fa[tt] = *(const bf16x8*)&As[wm + tt * 16 + m16][cs];
#pragma unroll
      for (int tm = 0; tm < 4; ++tm)
#pragma unroll
        for (int tn = 0; tn < 4; ++tn)
          acc[tm][tn] = __builtin_amdgcn_mfma_f32_16x16x32_bf16(fa[tm], fbr[kc * 4 + tn], acc[tm][tn], 0, 0, 0);
    }

    lgkm_barrier();   // B2: all waves' fa reads done before slab writes

    // ---- epilogue + wave-local slab stores (no cross-wave sync needed) ----
    // C/D layout: col=lane&15, row=g*4+r. Slab = 16 rows x 64 cols fp32,
    // swizzle chunk' = (col>>2) ^ rowInSlab.
    float* fSw = (float*)cur + wv * 2048;
#pragma unroll
    for (int tm = 0; tm < 4; ++tm) {
      float* slab = fSw + (tm & 1) * 1024;
#pragma unroll
      for (int tn = 0; tn < 4; ++tn) {
        int colq = tn * 16 + m16;          // quadrant-local col 0..63
        int j = bn * 128 + wn + colq;
        f32x4 c = acc[tm][tn];
#pragma unroll
        for (int r = 0; r < 4; ++r) {
          int rs = g * 4 + r;              // slab row 0..15
          int i = bm * 128 + wm + tm * 16 + rs;
          float s = c[r];
          float val = 0.0f;
          if (i == j) {
            val = 1.0f;
          } else if (s > 0.75f) {          // never taken; resolve in tail
            int idx = atomicAdd(&cold_cnt, 1);
            if (idx < COLD_CAP) cold_list[idx] = make_int4(i, j, __float_as_int(s), 0);
          }
          slab[rs * 64 + (((colq >> 2) ^ rs) << 2) + (colq & 3)] = val;
        }
      }
      lgkm_fence();   // slab writes complete before cross-lane readback
      // store slab: 4 instrs, each 4 rows x 256B contiguous segments
#pragma unroll
      for (int it = 0; it < 4; ++it) {
        int rs = it * 4 + g;
        f32x4 v = *(const f32x4*)&slab[rs * 64 + ((m16 ^ rs) << 2)];
        int grow = bm * 128 + wm + tm * 16 + rs;
        *(f32x4*)&out[(size_t)grow * N_NODES + bn * 128 + wn + m16 * 4] = v;
      }
    }
  }

  // ---- cold tail (block-local; empty for the given inputs). Every wave
  // drains its own stores so the patch write is ordered AFTER the earlier
  // 0-write to the same address (both from this block -> same CU/L2);
  // __syncthreads publishes the LDS list.
  asm volatile("s_waitcnt vmcnt(0)" ::: "memory");
  __syncthreads();
  {
    int n = cold_cnt;
    if (n > COLD_CAP) n = COLD_CAP;
    for (int e = tid; e < n; e += 256) {
      int i = cold_list[e].x, j = cold_list[e].y;
      float s = __int_as_float(cold_list[e].z);
      if (lsh_collide(z, H, i, j)) out[(size_t)i * N_NODES + j] = s;
    }
  }
}

extern "C" void kernel_launch(void* const* d_in, const int* in_sizes, int n_in,
                              void* d_out, int out_size, void* d_ws, size_t ws_size,
                              hipStream_t stream) {
  const float* z = (const float*)d_in[0];   // [8192, 128] fp32
  const float* H = (const float*)d_in[1];   // [128, 512] fp32
  // d_in[2] = edge_index, unused by the reference forward.
  float* out = (float*)d_out;               // [8192, 8192] fp32
  uint4* zn = (uint4*)d_ws;                 // 2 MiB normalized bf16, pre-swizzled
  (void)ws_size;

  norm_kernel<<<256, 256, 0, stream>>>(z, zn);
  sim_kernel<<<512, 256, 0, stream>>>(zn, z, H, out);
}